// Round 10
// baseline (61.857 us; speedup 1.0000x reference)
//
#include <hip/hip_runtime.h>
#include <stdint.h>

// Problem constants
#define N_ANCHOR 2048
#define DIM 128
#define NEG_PER 15
#define NZ 32768                    // 2048*16 candidate rows
#define INV_TEMP 3.3333333333333335f
#define LOG2E 1.4426950408889634f
#define LN2 0.6931471805599453f
#define TOTAL_ELEMS 67108864.0f
#define A_PRESCALE (INV_TEMP * LOG2E)   // folded into anchor normalization

#define BM 256                      // rows per block (4 waves x 64)
#define CPB 256                     // cols per block (8 tiles of 32)
#define NT 8
#define RB 8                        // 2048/256
#define CG 128                      // 32768/256
#define NBLK 1024

using bf16x8 = __attribute__((ext_vector_type(8))) __bf16;
using f32x16 = __attribute__((ext_vector_type(16))) float;

// ---------- helpers ----------
static __device__ __forceinline__ unsigned short f2bf(float f) {
  union { float f; unsigned u; } v; v.f = f;
  unsigned r = v.u + 0x7FFF + ((v.u >> 16) & 1);   // round-to-nearest-even
  return (unsigned short)(r >> 16);
}

// ---------- kernel 1: normalize ----------
// blocks [0,256): anchors -> row-major a_bf, prescaled by INV_TEMP*LOG2E.
// blocks [256,1280): one 32-col z tile each -> FRAGMENT-MAJOR z_bf via LDS
// transpose (stride 132 shorts: 2-way bank conflicts only, coalesced stores).
// Fragment layout (verified R7/R8): short addr(c,d) =
//   (c>>5)*4096 + (d>>4)*512 + ((c&31) + 32*((d>>3)&1))*8 + (d&7)
__global__ __launch_bounds__(256) void norm_kernel(
    const float* __restrict__ anchor, const float* __restrict__ pos,
    const float* __restrict__ neg, unsigned short* __restrict__ a_bf,
    unsigned short* __restrict__ z_bf) {
  const int bid = blockIdx.x, t = threadIdx.x;
  if (bid < 256) {                       // ---- anchor path (row-major) ----
    int row = bid * 8 + (t >> 5);
    int l32 = t & 31;
    float4 v = ((const float4*)(anchor + row * DIM))[l32];
    float s = v.x * v.x + v.y * v.y + v.z * v.z + v.w * v.w;
    #pragma unroll
    for (int o = 16; o >= 1; o >>= 1) s += __shfl_xor(s, o, 32);
    float sc = A_PRESCALE / fmaxf(sqrtf(s), 1e-12f);
    ushort4 o4;
    o4.x = f2bf(v.x * sc); o4.y = f2bf(v.y * sc);
    o4.z = f2bf(v.z * sc); o4.w = f2bf(v.w * sc);
    ((ushort4*)(a_bf + row * DIM))[l32] = o4;
  } else {                               // ---- z path (fragment-major) ----
    __shared__ unsigned short lz[32 * 132];
    const int T = bid - 256;             // tile = 32 z cols
    const int r = t >> 3, q = t & 7;     // 8 threads per col, 16 dims each
    const int c = T * 32 + r;
    const int j = c >> 4, k = c & 15;
    const float* src = (k == 0) ? (pos + (size_t)j * DIM)
                                : (neg + (size_t)(j * NEG_PER + k - 1) * DIM);
    float4 v[4];
    #pragma unroll
    for (int m = 0; m < 4; ++m) v[m] = *(const float4*)(src + q * 16 + m * 4);
    float s = 0.f;
    #pragma unroll
    for (int m = 0; m < 4; ++m)
      s += v[m].x * v[m].x + v[m].y * v[m].y + v[m].z * v[m].z + v[m].w * v[m].w;
    s += __shfl_xor(s, 1); s += __shfl_xor(s, 2); s += __shfl_xor(s, 4);
    float sc = 1.0f / fmaxf(sqrtf(s), 1e-12f);
    #pragma unroll
    for (int m = 0; m < 4; ++m) {
      ushort4 w;
      w.x = f2bf(v[m].x * sc); w.y = f2bf(v[m].y * sc);
      w.z = f2bf(v[m].z * sc); w.w = f2bf(v[m].w * sc);
      *(ushort4*)(lz + r * 132 + q * 16 + m * 4) = w;
    }
    __syncthreads();
    const size_t zb = (size_t)T * 4096;
    #pragma unroll
    for (int it = 0; it < 4; ++it) {
      int g    = it * 1024 + t * 4;      // short index within tile
      int ks   = g >> 9;
      int lane = (g >> 3) & 63;
      int jj   = g & 7;                  // 0 or 4
      int col  = lane & 31, kh = lane >> 5;
      int d    = ks * 16 + kh * 8 + jj;
      ushort4 w = *(const ushort4*)(lz + col * 132 + d);
      *(ushort4*)(z_bf + zb + g) = w;    // consecutive t -> consecutive 8B
    }
  }
}

// ---------- kernel 2: closed-form diagonal from RAW f32 inputs ----------
// dpart[i] = A_PRESCALE * <a_i/||a_i||, sum_k z_ik/||z_ik||>  (t-units)
// (verified R8)
__global__ __launch_bounds__(256) void diag_kernel(
    const float* __restrict__ anchor, const float* __restrict__ pos,
    const float* __restrict__ neg, float* __restrict__ dpart) {
  int i    = blockIdx.x * 4 + (threadIdx.x >> 6);
  int lane = threadIdx.x & 63;
  float2 a2 = ((const float2*)(anchor + i * DIM))[lane];
  float na = a2.x * a2.x + a2.y * a2.y;
  #pragma unroll
  for (int o = 32; o >= 1; o >>= 1) na += __shfl_xor(na, o);
  float sa = A_PRESCALE / fmaxf(sqrtf(na), 1e-12f);
  float s0 = 0.f, s1 = 0.f;
  #pragma unroll 1
  for (int k = 0; k < 16; ++k) {
    const float* zr = (k == 0) ? (pos + i * DIM)
                               : (neg + (i * NEG_PER + (k - 1)) * DIM);
    float2 z2 = ((const float2*)zr)[lane];
    float nz = z2.x * z2.x + z2.y * z2.y;
    #pragma unroll
    for (int o = 32; o >= 1; o >>= 1) nz += __shfl_xor(nz, o);
    float sz = 1.0f / fmaxf(sqrtf(nz), 1e-12f);
    s0 += z2.x * sz;
    s1 += z2.y * sz;
  }
  float d = (a2.x * sa) * s0 + (a2.y * sa) * s1;
  #pragma unroll
  for (int o = 32; o >= 1; o >>= 1) d += __shfl_xor(d, o);
  if (lane == 0) dpart[i] = d;
}

// ---------- kernel 3: GEMM + loss — no LDS, no barriers, reg pipeline ----
// R9 post-mortem: phase skeleton (gload_lds/vmcnt/barrier) pins each
// block-phase at ~3000cyc regardless of depth/waves. Removed entirely.
// Each wave: A frags in regs (once), B frags depth-1 register double-buffer
// (named bA/bB, static indices per rule #20): loads for tile t+1 issue
// before compute of tile t -> compiler emits counted vmcnt(8).
// Epilogue position-independent (diag handled by diag_kernel).
#define LOADB(dst, T_)                                                    \
  {                                                                       \
    const unsigned short* bp_ = Bt0 + (size_t)(T_) * 4096;                \
    _Pragma("unroll")                                                     \
    for (int ks = 0; ks < 8; ++ks)                                        \
      dst[ks] = *(const bf16x8*)(bp_ + ks * 512);                         \
  }

#define COMPUTE(bX)                                                       \
  {                                                                       \
    f32x16 acc0 = 0.0f, acc1 = 0.0f;                                      \
    _Pragma("unroll")                                                     \
    for (int ks = 0; ks < 8; ++ks) {                                      \
      acc0 = __builtin_amdgcn_mfma_f32_32x32x16_bf16(af[0][ks], bX[ks],   \
                                                     acc0, 0, 0, 0);      \
      acc1 = __builtin_amdgcn_mfma_f32_32x32x16_bf16(af[1][ks], bX[ks],   \
                                                     acc1, 0, 0, 0);      \
    }                                                                     \
    float st[4] = {0.f, 0.f, 0.f, 0.f};                                   \
    float sab[4] = {0.f, 0.f, 0.f, 0.f};                                  \
    float pr[4] = {1.f, 1.f, 1.f, 1.f};                                   \
    _Pragma("unroll")                                                     \
    for (int e = 0; e < 16; ++e) {                                        \
      float tv = acc0[e]; int r_ = e & 3;                                 \
      st[r_] += tv; sab[r_] += fabsf(tv);                                 \
      pr[r_] = fmaf(pr[r_], __builtin_amdgcn_exp2f(-fabsf(tv)), pr[r_]);  \
    }                                                                     \
    _Pragma("unroll")                                                     \
    for (int e = 0; e < 16; ++e) {                                        \
      float tv = acc1[e]; int r_ = e & 3;                                 \
      st[r_] += tv; sab[r_] += fabsf(tv);                                 \
      pr[r_] = fmaf(pr[r_], __builtin_amdgcn_exp2f(-fabsf(tv)), pr[r_]);  \
    }                                                                     \
    sumt  += (st[0] + st[1]) + (st[2] + st[3]);                           \
    sumab += (sab[0] + sab[1]) + (sab[2] + sab[3]);                       \
    logacc += __builtin_amdgcn_logf((pr[0] * pr[1]) * (pr[2] * pr[3]));   \
  }

__global__ __launch_bounds__(256) void gemm_loss_kernel(
    const unsigned short* __restrict__ a_bf,
    const unsigned short* __restrict__ z_bf,
    float* __restrict__ partial) {
  __shared__ float red[4];

  const int t    = threadIdx.x;
  const int bid  = blockIdx.x;
  // bijective XCD swizzle: XCD x covers cgi in [16x,16x+16), all 8 rb ->
  // each B tile read by 8 blocks of the SAME XCD (L2-local).
  const int lg   = ((bid & 7) << 7) | (bid >> 3);
  const int rb   = lg & 7;
  const int cgi  = lg >> 3;
  const int wave = t >> 6;
  const int lane = t & 63;

  // A fragments: af[i2][ks] = a[rb*256 + wave*64 + i2*32 + (lane&31)]
  //                             [ks*16 + (lane>>5)*8 .. +8]   (verified R7)
  bf16x8 af[2][8];
  {
    const unsigned short* Ar =
        a_bf + (size_t)(rb * BM + wave * 64 + (lane & 31)) * DIM +
        (lane >> 5) * 8;
    #pragma unroll
    for (int i = 0; i < 2; ++i)
      #pragma unroll
      for (int ks = 0; ks < 8; ++ks)
        af[i][ks] = *(const bf16x8*)(Ar + i * 32 * DIM + ks * 16);
  }

  const unsigned short* Bt0 =
      z_bf + (size_t)(cgi * NT) * 4096 + lane * 8;

  bf16x8 bA[8], bB[8];
  LOADB(bA, 0)

  float sumt = 0.f, sumab = 0.f, logacc = 0.f;

  #pragma unroll 1
  for (int tt = 0; tt < NT; tt += 2) {
    LOADB(bB, tt + 1)          // issue next tile's 8 loads, then compute
    COMPUTE(bA)
    if (tt + 2 < NT) LOADB(bA, tt + 2)
    COMPUTE(bB)
  }

  float local = 0.5f * (sumt + sumab) + logacc;
  #pragma unroll
  for (int o = 32; o >= 1; o >>= 1) local += __shfl_xor(local, o);
  if (lane == 0) red[wave] = local;
  __syncthreads();
  if (t == 0) partial[bid] = (red[0] + red[1]) + (red[2] + red[3]);
}

// ---------- kernel 4: final reduction ----------
__global__ __launch_bounds__(256) void reduce_kernel(
    const float* __restrict__ partial, const float* __restrict__ dpart,
    float* __restrict__ out) {
  int t = threadIdx.x;
  float s = 0.0f;
  for (int i = t; i < NBLK; i += 256) s += partial[i];
  for (int i = t; i < N_ANCHOR; i += 256) s -= dpart[i];
  #pragma unroll
  for (int o = 32; o >= 1; o >>= 1) s += __shfl_xor(s, o);
  __shared__ float red[4];
  if ((t & 63) == 0) red[t >> 6] = s;
  __syncthreads();
  if (t == 0)
    out[0] = ((red[0] + red[1]) + (red[2] + red[3])) * (LN2 / TOTAL_ELEMS);
}

extern "C" void kernel_launch(void* const* d_in, const int* in_sizes, int n_in,
                              void* d_out, int out_size, void* d_ws, size_t ws_size,
                              hipStream_t stream) {
  const float* anchor = (const float*)d_in[0];
  const float* pos    = (const float*)d_in[1];
  const float* neg    = (const float*)d_in[2];
  char* ws = (char*)d_ws;
  unsigned short* a_bf = (unsigned short*)ws;                    // 512 KB
  unsigned short* z_bf = (unsigned short*)(ws + 524288);         // 8 MB frag-major
  float* partial       = (float*)(ws + 524288 + 8388608);        // 4 KB
  float* dpart         = (float*)(ws + 524288 + 8388608 + 4096); // 8 KB

  norm_kernel<<<dim3(1280), dim3(256), 0, stream>>>(
      anchor, pos, neg, a_bf, z_bf);
  diag_kernel<<<dim3(N_ANCHOR / 4), dim3(256), 0, stream>>>(
      anchor, pos, neg, dpart);
  gemm_loss_kernel<<<dim3(NBLK), dim3(256), 0, stream>>>(a_bf, z_bf, partial);
  reduce_kernel<<<dim3(1), dim3(256), 0, stream>>>(partial, dpart,
                                                   (float*)d_out);
}